// Round 1
// baseline (5001.479 us; speedup 1.0000x reference)
//
#include <hip/hip_runtime.h>

#define NK 256
#define BB 128
#define CC 10
#define LL 16384
#define EPSV 1e-10f
#define G 16

// ---------------- ws layout (floats) ----------------
// [0, 1280)      inv  per (b*C+c)
// [1280, 2560)   shift per (b*C+c)
// then ints: wbase[256], cbase[256]

__global__ __launch_bounds__(256) void stats_kernel(const float* __restrict__ x,
                                                    float* __restrict__ wsf) {
    int row = blockIdx.x;  // b*C + c  (0..1279)
    const float4* x4 = (const float4*)(x + (size_t)row * LL);
    int tid = threadIdx.x;
    float s = 0.f, s2 = 0.f;
    for (int i = tid; i < LL / 4; i += 256) {
        float4 v = x4[i];
        s  += v.x + v.y + v.z + v.w;
        s2 += v.x * v.x + v.y * v.y + v.z * v.z + v.w * v.w;
    }
    for (int off = 32; off; off >>= 1) {
        s  += __shfl_down(s, off);
        s2 += __shfl_down(s2, off);
    }
    __shared__ float as_[4], as2_[4];
    int wv = tid >> 6, ln = tid & 63;
    if (ln == 0) { as_[wv] = s; as2_[wv] = s2; }
    __syncthreads();
    if (tid == 0) {
        float S  = as_[0] + as_[1] + as_[2] + as_[3];
        float S2 = as2_[0] + as2_[1] + as2_[2] + as2_[3];
        float mean = S / (float)LL;
        float var  = (S2 - (float)LL * mean * mean) / (float)(LL - 1);
        var = fmaxf(var, 0.f);
        float inv = 1.f / (sqrtf(var) + EPSV);
        wsf[row]        = inv;
        wsf[1280 + row] = -mean * inv;
    }
}

__global__ __launch_bounds__(256) void prefix_kernel(const int* __restrict__ lengths,
                                                     const int* __restrict__ ncis,
                                                     int* __restrict__ wbase,
                                                     int* __restrict__ cbase) {
    __shared__ int s1[NK], s2[NK];
    int k = threadIdx.x;
    int v1 = lengths[k] * ncis[k];
    int v2 = ncis[k];
    s1[k] = v1; s2[k] = v2;
    for (int off = 1; off < NK; off <<= 1) {
        __syncthreads();
        int a = (k >= off) ? s1[k - off] : 0;
        int b = (k >= off) ? s2[k - off] : 0;
        __syncthreads();
        s1[k] += a; s2[k] += b;
    }
    __syncthreads();
    wbase[k] = s1[k] - v1;  // exclusive prefix
    cbase[k] = s2[k] - v2;
}

__device__ __forceinline__ void merge_sm(float& m1, float& s1, float& w1,
                                         float m2, float s2, float w2) {
    float M  = fmaxf(m1, m2);
    float e1 = __expf(1000.f * (m1 - M));
    float e2 = __expf(1000.f * (m2 - M));
    s1 = s1 * e1 + s2 * e2;
    w1 = w1 * e1 + w2 * e2;
    m1 = M;
}

template <int LEN>
__device__ __forceinline__ void conv_run(
    const float* __restrict__ x,
    const float* wsm, const int* choff, const float* cinv, const float* csh,
    float* rm, float* rs, float* rw, int* rc,
    int d, int ms, int Lout, int nci, float bias,
    float* __restrict__ out, int b, int k) {
    constexpr int W = G + LEN - 1;
    const int tid = threadIdx.x;

    int cnt = 0;
    float mx = -3.4e38f, ss = 0.f, ww = 0.f;

    int Qmax = (Lout + d - 1) / d;
    int NB   = (Qmax + G - 1) / G;
    int ntot = d * NB;

    for (int n0 = 0; n0 < ntot; n0 += 256) {
        int n = n0 + tid;
        bool active = (n < ntot);
        int nn  = active ? n : 0;
        int rho = nn % d;
        int qb  = (nn / d) * G;
        int m0  = qb - ms;

        float acc[G];
#pragma unroll
        for (int g = 0; g < G; ++g) acc[g] = 0.f;

        for (int ci = 0; ci < nci; ++ci) {
            const float* xc = x + choff[ci];
            float inv = cinv[ci], sh = csh[ci];
            float win[W];
#pragma unroll
            for (int i = 0; i < W; ++i) {
                int u = rho + (m0 + i) * d;
                bool v = (unsigned)u < (unsigned)LL;
                float xv = xc[v ? u : 0];
                win[i] = v ? fmaf(xv, inv, sh) : 0.f;
            }
            float wreg[LEN];
#pragma unroll
            for (int j = 0; j < LEN; ++j) wreg[j] = wsm[ci * LEN + j];
#pragma unroll
            for (int j = 0; j < LEN; ++j) {
#pragma unroll
                for (int g = 0; g < G; ++g)
                    acc[g] = fmaf(wreg[j], win[g + j], acc[g]);
            }
        }

        if (active) {
#pragma unroll
            for (int g = 0; g < G; ++g) {
                int t = (qb + g) * d + rho;
                if (t < Lout) {
                    float y = acc[g] + bias;
                    cnt += (y > 0.f) ? 1 : 0;
                    if (y > mx) {
                        float f = __expf(1000.f * (mx - y));
                        ss *= f; ww *= f; mx = y;
                    }
                    float e = __expf(1000.f * (y - mx));
                    ss += e; ww += e * y;
                }
            }
        }
    }

    // block reduction: wave-level first
    for (int off = 32; off; off >>= 1) {
        float m2 = __shfl_down(mx, off);
        float s2 = __shfl_down(ss, off);
        float w2 = __shfl_down(ww, off);
        int   c2 = __shfl_down(cnt, off);
        merge_sm(mx, ss, ww, m2, s2, w2);
        cnt += c2;
    }
    int wv = tid >> 6, ln = tid & 63;
    if (ln == 0) { rm[wv] = mx; rs[wv] = ss; rw[wv] = ww; rc[wv] = cnt; }
    __syncthreads();
    if (tid == 0) {
        for (int i = 1; i < 4; ++i) {
            merge_sm(mx, ss, ww, rm[i], rs[i], rw[i]);
            cnt += rc[i];
        }
        float ppv = (float)cnt / (float)Lout;
        float mxv = ww / ss;
        size_t o = (size_t)b * (2 * NK) + 2 * k;
        out[o]     = ppv;
        out[o + 1] = mxv;
    }
}

__global__ __launch_bounds__(256) void conv_kernel(
    const float* __restrict__ x, const float* __restrict__ weights,
    const float* __restrict__ biases,
    const int* __restrict__ lengths, const int* __restrict__ dil,
    const int* __restrict__ pad, const int* __restrict__ ncis,
    const int* __restrict__ chidx,
    const float* __restrict__ wsf, const int* __restrict__ wbase,
    const int* __restrict__ cbase, float* __restrict__ out) {
    int k = blockIdx.x, b = blockIdx.y;
    __shared__ float wsm[CC * 11];
    __shared__ int   choff[CC];
    __shared__ float cinv[CC], csh[CC];
    __shared__ float rm[4], rs[4], rw[4];
    __shared__ int   rc[4];

    int tid = threadIdx.x;
    int len = lengths[k], d = dil[k], p = pad[k], nci = ncis[k];
    int wb = wbase[k], cb = cbase[k];

    if (tid < nci) {
        int ch = chidx[cb + tid];
        choff[tid] = (b * CC + ch) * LL;
        cinv[tid]  = wsf[b * CC + ch];
        csh[tid]   = wsf[1280 + b * CC + ch];
    }
    int nw = nci * len;
    for (int i = tid; i < nw; i += 256) wsm[i] = weights[wb + i];
    __syncthreads();

    int span = (len - 1) * d;
    int Lout = LL + 2 * p - span;
    int ms   = p / d;  // p is either 0 or ((len-1)/2)*d
    float bias = biases[k];

    switch (len) {
        case 7:
            conv_run<7>(x, wsm, choff, cinv, csh, rm, rs, rw, rc,
                        d, ms, Lout, nci, bias, out, b, k);
            break;
        case 9:
            conv_run<9>(x, wsm, choff, cinv, csh, rm, rs, rw, rc,
                        d, ms, Lout, nci, bias, out, b, k);
            break;
        default:
            conv_run<11>(x, wsm, choff, cinv, csh, rm, rs, rw, rc,
                         d, ms, Lout, nci, bias, out, b, k);
            break;
    }
}

extern "C" void kernel_launch(void* const* d_in, const int* in_sizes, int n_in,
                              void* d_out, int out_size, void* d_ws, size_t ws_size,
                              hipStream_t stream) {
    const float* x       = (const float*)d_in[0];
    const float* weights = (const float*)d_in[1];
    const float* biases  = (const float*)d_in[2];
    const int* lengths   = (const int*)d_in[3];
    const int* dil       = (const int*)d_in[4];
    const int* pad       = (const int*)d_in[5];
    const int* ncis      = (const int*)d_in[6];
    const int* chidx     = (const int*)d_in[7];
    float* out = (float*)d_out;

    float* wsf  = (float*)d_ws;
    int* wbase  = (int*)((char*)d_ws + 2560 * sizeof(float));
    int* cbase  = wbase + NK;

    stats_kernel<<<dim3(BB * CC), dim3(256), 0, stream>>>(x, wsf);
    prefix_kernel<<<dim3(1), dim3(256), 0, stream>>>(lengths, ncis, wbase, cbase);
    dim3 grid(NK, BB);
    conv_kernel<<<grid, dim3(256), 0, stream>>>(x, weights, biases, lengths, dil,
                                                pad, ncis, chidx, wsf, wbase,
                                                cbase, out);
}

// Round 2
// 4675.026 us; speedup vs baseline: 1.0698x; 1.0698x over previous
//
#include <hip/hip_runtime.h>

#define NK 256
#define BB 128
#define CC 10
#define LL 16384
#define EPSV 1e-10f
#define G 16
#define DTHR 16
#define EXPCUT 0.0886f

__device__ __forceinline__ int padidx(int a) { return a + (a >> 4); }

__device__ __forceinline__ void accum_out(float y, int& cnt, float& mx,
                                          float& ss, float& ww) {
    if (y > 0.f) ++cnt;
    if (y > mx) {
        float f = __expf(1000.f * (mx - y));
        ss = ss * f + 1.f;
        ww = ww * f + y;
        mx = y;
    } else if (y > mx - EXPCUT) {
        float e = __expf(1000.f * (y - mx));
        ss += e;
        ww += e * y;
    }
}

__device__ __forceinline__ void merge_sm(float& m1, float& s1, float& w1,
                                         float m2, float s2, float w2) {
    float M = fmaxf(m1, m2);
    float e1 = __expf(1000.f * (m1 - M));
    float e2 = __expf(1000.f * (m2 - M));
    s1 = s1 * e1 + s2 * e2;
    w1 = w1 * e1 + w2 * e2;
    m1 = M;
}

__device__ __forceinline__ void block_finish(int cnt, float mx, float ss, float ww,
                                             float* rm, float* rs, float* rw, int* rc,
                                             int Lout, float* out, int b, int k) {
    int tid = threadIdx.x;
    for (int off = 32; off; off >>= 1) {
        float m2 = __shfl_down(mx, off);
        float s2 = __shfl_down(ss, off);
        float w2 = __shfl_down(ww, off);
        int c2 = __shfl_down(cnt, off);
        merge_sm(mx, ss, ww, m2, s2, w2);
        cnt += c2;
    }
    int wv = tid >> 6, ln = tid & 63;
    if (ln == 0) { rm[wv] = mx; rs[wv] = ss; rw[wv] = ww; rc[wv] = cnt; }
    __syncthreads();
    if (tid == 0) {
        for (int i = 1; i < 4; ++i) {
            merge_sm(mx, ss, ww, rm[i], rs[i], rw[i]);
            cnt += rc[i];
        }
        size_t o = (size_t)b * (2 * NK) + 2 * k;
        out[o] = (float)cnt / (float)Lout;
        out[o + 1] = ww / ss;
    }
}

__global__ __launch_bounds__(256) void stats_kernel(const float* __restrict__ x,
                                                    float* __restrict__ wsf) {
    int row = blockIdx.x;
    const float4* x4 = (const float4*)(x + (size_t)row * LL);
    int tid = threadIdx.x;
    float s = 0.f, s2 = 0.f;
    for (int i = tid; i < LL / 4; i += 256) {
        float4 v = x4[i];
        s += v.x + v.y + v.z + v.w;
        s2 += v.x * v.x + v.y * v.y + v.z * v.z + v.w * v.w;
    }
    for (int off = 32; off; off >>= 1) {
        s += __shfl_down(s, off);
        s2 += __shfl_down(s2, off);
    }
    __shared__ float as_[4], as2_[4];
    int wv = tid >> 6, ln = tid & 63;
    if (ln == 0) { as_[wv] = s; as2_[wv] = s2; }
    __syncthreads();
    if (tid == 0) {
        float S = as_[0] + as_[1] + as_[2] + as_[3];
        float S2 = as2_[0] + as2_[1] + as2_[2] + as2_[3];
        float mean = S / (float)LL;
        float var = (S2 - (float)LL * mean * mean) / (float)(LL - 1);
        var = fmaxf(var, 0.f);
        float inv = 1.f / (sqrtf(var) + EPSV);
        wsf[row] = inv;
        wsf[1280 + row] = -mean * inv;
    }
}

__global__ __launch_bounds__(256) void prefix_kernel(const int* __restrict__ lengths,
                                                     const int* __restrict__ ncis,
                                                     int* __restrict__ wbase,
                                                     int* __restrict__ cbase) {
    __shared__ int s1[NK], s2[NK];
    int k = threadIdx.x;
    int v1 = lengths[k] * ncis[k];
    int v2 = ncis[k];
    s1[k] = v1; s2[k] = v2;
    for (int off = 1; off < NK; off <<= 1) {
        __syncthreads();
        int a = (k >= off) ? s1[k - off] : 0;
        int b = (k >= off) ? s2[k - off] : 0;
        __syncthreads();
        s1[k] += a; s2[k] += b;
    }
    __syncthreads();
    wbase[k] = s1[k] - v1;
    cbase[k] = s2[k] - v2;
}

// ---------------- large-d path: direct global windows (coalesced for d>=16) ---
template <int LEN>
__device__ __forceinline__ void conv_run(
    const float* __restrict__ x,
    const float* wsm, const int* choff, const float* cinv, const float* csh,
    float* rm, float* rs, float* rw, int* rc,
    int d, int ms, int Lout, int nci, float bias,
    float* __restrict__ out, int b, int k) {
    constexpr int W = G + LEN - 1;
    const int tid = threadIdx.x;

    int cnt = 0;
    float mx = -3.4e38f, ss = 0.f, ww = 0.f;

    int Qmax = (Lout + d - 1) / d;
    int NB = (Qmax + G - 1) / G;
    int ntot = d * NB;

    for (int n0 = 0; n0 < ntot; n0 += 256) {
        int n = n0 + tid;
        bool active = (n < ntot);
        int nn = active ? n : 0;
        int rho = nn % d;
        int qb = (nn / d) * G;
        int m0 = qb - ms;

        float acc[G];
#pragma unroll
        for (int g = 0; g < G; ++g) acc[g] = 0.f;

        for (int ci = 0; ci < nci; ++ci) {
            const float* xc = x + choff[ci];
            float inv = cinv[ci], sh = csh[ci];
            float win[W];
#pragma unroll
            for (int i = 0; i < W; ++i) {
                int u = rho + (m0 + i) * d;
                bool v = (unsigned)u < (unsigned)LL;
                float xv = xc[v ? u : 0];
                win[i] = v ? fmaf(xv, inv, sh) : 0.f;
            }
            float wreg[LEN];
#pragma unroll
            for (int j = 0; j < LEN; ++j) wreg[j] = wsm[ci * LEN + j];
#pragma unroll
            for (int j = 0; j < LEN; ++j) {
#pragma unroll
                for (int g = 0; g < G; ++g)
                    acc[g] = fmaf(wreg[j], win[g + j], acc[g]);
            }
        }

        if (active) {
#pragma unroll
            for (int g = 0; g < G; ++g) {
                int t = (qb + g) * d + rho;
                if (t < Lout) accum_out(acc[g] + bias, cnt, mx, ss, ww);
            }
        }
    }
    block_finish(cnt, mx, ss, ww, rm, rs, rw, rc, Lout, out, b, k);
}

// ---------------- small-d path: LDS-staged decimated-transpose ----------------
template <int LEN>
__device__ __forceinline__ void conv_lds(
    const float* __restrict__ x, float* xl,
    const float* wsm, const int* choff, const float* cinv, const float* csh,
    float* rm, float* rs, float* rw, int* rc,
    int d, int ms, int Lout, int nci, float bias,
    float* __restrict__ out, int b, int k) {
    constexpr int W = G + LEN - 1;
    const int tid = threadIdx.x;

    int cnt = 0;
    float mx = -3.4e38f, ss = 0.f, ww = 0.f;

    int qpt = 256 / d;        // q-blocks per tile per rho
    int MT = qpt * G;         // m-values per tile per rho
    int Mw = MT + LEN - 1;    // staged m-window per rho
    int stot = d * Mw;        // staged floats per tile per channel
    int Qmax = (Lout + d - 1) / d;
    int nit = d * qpt;        // work items per tile (<=256)

    bool active = tid < nit;
    int rho = 0, qi = 0;
    if (active) { rho = tid / qpt; qi = tid - rho * qpt; }

    // staging iteration decomposition (s = tid + 256*j)
    int rr0 = tid % d, mm0 = tid / d;
    int dr = 256 % d, dm = 256 / d;

    for (int qt = 0; qt < Qmax; qt += MT) {
        float acc[G];
#pragma unroll
        for (int g = 0; g < G; ++g) acc[g] = 0.f;
        int tb = d * (qt - ms);  // t of (rho=0, mloc=0); == 0 mod d

        for (int ci = 0; ci < nci; ++ci) {
            __syncthreads();
            const float* xc = x + choff[ci];
            float inv = cinv[ci], sh = csh[ci];
            int rr = rr0, mm = mm0;
            for (int s = tid; s < stot; s += 256) {
                int t = tb + s;
                if ((unsigned)t < (unsigned)LL) {
                    int a = rr * Mw + mm;
                    xl[padidx(a)] = fmaf(xc[t], inv, sh);
                }
                rr += dr; mm += dm;
                if (rr >= d) { rr -= d; ++mm; }
            }
            __syncthreads();

            if (active) {
                int abase = rho * Mw + qi * G;
                int m0 = qt + qi * G - ms;
                float wreg[LEN];
#pragma unroll
                for (int j = 0; j < LEN; ++j) wreg[j] = wsm[ci * LEN + j];
                float win[W];
#pragma unroll
                for (int i = 0; i < W; ++i) {
                    int u = rho + (m0 + i) * d;
                    float lv = xl[padidx(abase + i)];
                    win[i] = ((unsigned)u < (unsigned)LL) ? lv : 0.f;
                }
#pragma unroll
                for (int j = 0; j < LEN; ++j) {
#pragma unroll
                    for (int g = 0; g < G; ++g)
                        acc[g] = fmaf(wreg[j], win[g + j], acc[g]);
                }
            }
        }

        if (active) {
            int qb = qt + qi * G;
#pragma unroll
            for (int g = 0; g < G; ++g) {
                int t = (qb + g) * d + rho;
                if (t < Lout) accum_out(acc[g] + bias, cnt, mx, ss, ww);
            }
        }
    }
    block_finish(cnt, mx, ss, ww, rm, rs, rw, rc, Lout, out, b, k);
}

__global__ __launch_bounds__(256) void conv_kernel(
    const float* __restrict__ x, const float* __restrict__ weights,
    const float* __restrict__ biases,
    const int* __restrict__ lengths, const int* __restrict__ dil,
    const int* __restrict__ pad, const int* __restrict__ ncis,
    const int* __restrict__ chidx,
    const float* __restrict__ wsf, const int* __restrict__ wbase,
    const int* __restrict__ cbase, float* __restrict__ out) {
    int k = blockIdx.x, b = blockIdx.y;
    __shared__ float xl[4608];  // 18 KB staged tile (small-d path only)
    __shared__ float wsm[CC * 11];
    __shared__ int choff[CC];
    __shared__ float cinv[CC], csh[CC];
    __shared__ float rm[4], rs[4], rw[4];
    __shared__ int rc[4];

    int tid = threadIdx.x;
    int len = lengths[k], d = dil[k], p = pad[k], nci = ncis[k];
    int wb = wbase[k], cb = cbase[k];

    if (tid < nci) {
        int ch = chidx[cb + tid];
        choff[tid] = (b * CC + ch) * LL;
        cinv[tid] = wsf[b * CC + ch];
        csh[tid] = wsf[1280 + b * CC + ch];
    }
    int nw = nci * len;
    for (int i = tid; i < nw; i += 256) wsm[i] = weights[wb + i];
    __syncthreads();

    int span = (len - 1) * d;
    int Lout = LL + 2 * p - span;
    int ms = p / d;
    float bias = biases[k];

    if (d < DTHR) {
        switch (len) {
            case 7:
                conv_lds<7>(x, xl, wsm, choff, cinv, csh, rm, rs, rw, rc,
                            d, ms, Lout, nci, bias, out, b, k);
                break;
            case 9:
                conv_lds<9>(x, xl, wsm, choff, cinv, csh, rm, rs, rw, rc,
                            d, ms, Lout, nci, bias, out, b, k);
                break;
            default:
                conv_lds<11>(x, xl, wsm, choff, cinv, csh, rm, rs, rw, rc,
                             d, ms, Lout, nci, bias, out, b, k);
                break;
        }
    } else {
        switch (len) {
            case 7:
                conv_run<7>(x, wsm, choff, cinv, csh, rm, rs, rw, rc,
                            d, ms, Lout, nci, bias, out, b, k);
                break;
            case 9:
                conv_run<9>(x, wsm, choff, cinv, csh, rm, rs, rw, rc,
                            d, ms, Lout, nci, bias, out, b, k);
                break;
            default:
                conv_run<11>(x, wsm, choff, cinv, csh, rm, rs, rw, rc,
                             d, ms, Lout, nci, bias, out, b, k);
                break;
        }
    }
}

extern "C" void kernel_launch(void* const* d_in, const int* in_sizes, int n_in,
                              void* d_out, int out_size, void* d_ws, size_t ws_size,
                              hipStream_t stream) {
    const float* x = (const float*)d_in[0];
    const float* weights = (const float*)d_in[1];
    const float* biases = (const float*)d_in[2];
    const int* lengths = (const int*)d_in[3];
    const int* dil = (const int*)d_in[4];
    const int* pad = (const int*)d_in[5];
    const int* ncis = (const int*)d_in[6];
    const int* chidx = (const int*)d_in[7];
    float* out = (float*)d_out;

    float* wsf = (float*)d_ws;
    int* wbase = (int*)((char*)d_ws + 2560 * sizeof(float));
    int* cbase = wbase + NK;

    stats_kernel<<<dim3(BB * CC), dim3(256), 0, stream>>>(x, wsf);
    prefix_kernel<<<dim3(1), dim3(256), 0, stream>>>(lengths, ncis, wbase, cbase);
    dim3 grid(NK, BB);
    conv_kernel<<<grid, dim3(256), 0, stream>>>(x, weights, biases, lengths, dil,
                                                pad, ncis, chidx, wsf, wbase,
                                                cbase, out);
}